// Round 5
// baseline (48.507 us; speedup 1.0000x reference)
//
#include <hip/hip_runtime.h>
#include <math.h>

// SphericalHarmonicsLayer, specialized for H=256, max_order=3 (derived from sizes).
//
// out[b,n] is an [H,17] tile, flat row = (b*N+n)*H + h, 17 floats per row:
//   j=0..15: real spherical harmonics l=0..3 (reference convention incl.
//            Condon-Shortley phase inside P_l^m), j=16: time channel.
//
// Roofline: 285 MB f32 writes, ~0.2 MB reads -> HBM-write-bound.
// R2: nontemporal stores = 25% REGRESSION (reverted). R3: per-wave staging
// == block-barrier version (47.5 vs 48.0 us) — wave overlap already hides it.
// R4: persistent grid (2048 blocks = 8/CU, fully co-resident), 8 consecutive
// bn per block. Weights live in registers across iterations; loop software-
// pipelines compute(i+1) against store-drain(i); constant row[0] hoisted.
//
// Per-wave LDS chunk [64][17] (stride-17 odd -> conflict-free), coalesced
// plain float4 stores. Intra-wave ds ordering: in-order DS pipe per wave +
// s_waitcnt lgkmcnt(0) before cross-lane reads.

namespace {
constexpr int kH = 256;
constexpr int kPerRow = 17;                 // (L+1)^2 + 1 with L=3
constexpr int kWaveFloats = 64 * kPerRow;   // 1088 floats = 272 float4
constexpr int kWaveVec4 = kWaveFloats / 4;  // 272
constexpr int kBlocks = 2048;               // 8 blocks/CU on 256 CUs

typedef float f32x4 __attribute__((ext_vector_type(4)));

__global__ __launch_bounds__(kH) void sh_l3_kernel(
    const float* __restrict__ x,
    const float* __restrict__ w_theta, const float* __restrict__ b_theta,
    const float* __restrict__ w_phi,   const float* __restrict__ b_phi,
    const float* __restrict__ w_time,  const float* __restrict__ b_time,
    float* __restrict__ out, int BN, int iters)
{
    __shared__ __align__(16) float lds[kH * kPerRow];  // 17408 B

    const int h    = threadIdx.x;
    const int wave = h >> 6;
    const int lane = h & 63;

    // Weights: loaded ONCE per thread, reused across all iterations.
    const float wt = w_theta[h], bt = b_theta[h];
    const float wp = w_phi[h],   bp = b_phi[h];
    const float wm = w_time[h],  bm = b_time[h];

    float* row = &lds[wave * kWaveFloats + lane * kPerRow];
    const f32x4* lds4 = (const f32x4*)(lds + wave * kWaveFloats);

    // Constant across iterations; LDS chunk is private to this wave.
    row[0] = 0.28209479177387814f;

    const int bn0 = blockIdx.x * iters;
#pragma unroll 1
    for (int it = 0; it < iters; ++it) {
        const int bn = bn0 + it;
        if (bn >= BN) break;

        // Block-uniform scalar inputs (L2-resident after first touch).
        const float xt = x[bn * 3 + 0];
        const float xp = x[bn * 3 + 1];
        const float xm = x[bn * 3 + 2];

        const float theta = fmaf(xt, wt, bt);
        const float phi   = fmaf(xp, wp, bp);
        const float tmv   = fmaf(xm, wm, bm);

        const float ct  = cosf(theta);
        const float ct2 = ct * ct;
        const float s   = sqrtf(fmaxf(1.0f - ct2, 0.0f));  // sin(theta) >= 0
        const float ss  = s * s;
        const float sss = ss * s;

        float sp, cp;
        sincosf(phi, &sp, &cp);
        const float c2  = fmaf(2.0f * cp, cp, -1.0f);  // cos 2phi
        const float sn2 = 2.0f * sp * cp;              // sin 2phi
        const float c3  = c2 * cp - sn2 * sp;          // cos 3phi
        const float sn3 = sn2 * cp + c2 * sp;          // sin 3phi

        // K(l,m)*sqrt2 folded with Legendre constants; Condon-Shortley signs:
        //   P11 = -s, P21 = -3 s ct, P31 = -1.5 s (5ct^2-1), P33 = -15 s^3
        row[1]  = -0.4886025119029199f * s * sp;                              // (1,-1)
        row[2]  = 0.4886025119029199f * ct;                                   // (1, 0)
        row[3]  = -0.4886025119029199f * s * cp;                              // (1, 1)
        row[4]  = 0.5462742152960396f * ss * sn2;                             // (2,-2)
        row[5]  = -1.0925484305920792f * (s * ct) * sp;                       // (2,-1)
        row[6]  = 0.31539156525252005f * fmaf(3.0f, ct2, -1.0f);              // (2, 0)
        row[7]  = -1.0925484305920792f * (s * ct) * cp;                       // (2, 1)
        row[8]  = 0.5462742152960396f * ss * c2;                              // (2, 2)
        row[9]  = -0.5900435899266435f * sss * sn3;                           // (3,-3)
        row[10] = 1.445305721320277f * (ss * ct) * sn2;                       // (3,-2)
        row[11] = -0.45704579946446577f * (s * fmaf(5.0f, ct2, -1.0f)) * sp;  // (3,-1)
        row[12] = 0.3731763325901154f * ct * fmaf(5.0f, ct2, -3.0f);          // (3, 0)
        row[13] = -0.45704579946446577f * (s * fmaf(5.0f, ct2, -1.0f)) * cp;  // (3, 1)
        row[14] = 1.445305721320277f * (ss * ct) * c2;                        // (3, 2)
        row[15] = -0.5900435899266435f * sss * c3;                            // (3, 3)
        row[16] = tmv;

        // This wave's DS writes drain (in-order DS pipe); clobber pins the
        // cross-lane LDS reads below after the writes above.
        asm volatile("s_waitcnt lgkmcnt(0)" ::: "memory");

        // Coalesced copy of this wave's 4352 B chunk: 272 float4 / 64 lanes.
        f32x4* out4 = (f32x4*)(out + (size_t)bn * (kH * kPerRow) + wave * kWaveFloats);
#pragma unroll
        for (int i = 0; i < 4; ++i)
            out4[i * 64 + lane] = lds4[i * 64 + lane];
        if (lane < kWaveVec4 - 256)  // 16 tail float4s
            out4[256 + lane] = lds4[256 + lane];
        // No trailing barrier: next iter's ds_writes genuinely alias the
        // ds_reads above, so the compiler preserves order; HW DS pipe is
        // in-order per wave. Next iter's VALU compute is free to hoist.
    }
}
}  // namespace

extern "C" void kernel_launch(void* const* d_in, const int* in_sizes, int n_in,
                              void* d_out, int out_size, void* d_ws, size_t ws_size,
                              hipStream_t stream) {
    const float* x       = (const float*)d_in[0];
    const float* w_theta = (const float*)d_in[1];
    const float* b_theta = (const float*)d_in[2];
    const float* w_phi   = (const float*)d_in[3];
    const float* b_phi   = (const float*)d_in[4];
    const float* w_time  = (const float*)d_in[5];
    const float* b_time  = (const float*)d_in[6];
    float* out = (float*)d_out;

    const int BN = in_sizes[0] / 3;            // B*N = 16384
    const int nb = BN < kBlocks ? BN : kBlocks;
    const int iters = (BN + nb - 1) / nb;      // 8 for BN=16384
    sh_l3_kernel<<<dim3(nb), dim3(kH), 0, stream>>>(
        x, w_theta, b_theta, w_phi, b_phi, w_time, b_time, out, BN, iters);
}

// Round 6
// 47.825 us; speedup vs baseline: 1.0143x; 1.0143x over previous
//
#include <hip/hip_runtime.h>
#include <math.h>

// SphericalHarmonicsLayer, specialized for H=256, max_order=3 (derived from sizes).
//
// out[b,n] is an [H,17] tile, flat row = (b*N+n)*H + h, 17 floats per row:
//   j=0..15: real spherical harmonics l=0..3 (reference convention incl.
//            Condon-Shortley phase inside P_l^m), j=16: time channel.
//
// Roofline: 285 MB f32 writes, ~0.2 MB reads -> HBM-write-bound.
// Ladder: R1 47.5us (block-barrier). R2 nt-stores 59.6us REGRESSION (revert).
// R3 per-wave no-barrier 48.0us (null). R4 persistent grid 48.5us (null).
// R5: libm cosf/sincosf (Payne-Hanek, ~100s of VALU instrs) -> native HW trig
// __sinf/__cosf (v_mul+v_fract+v_sin_f32, ~4 instrs). Tests whether exposed
// per-iteration VALU (not write BW) is the 6.0-vs-7.0 TB/s gap.
// Accuracy: |angles| <~ 8, native err ~1e-5 << 9.9e-2 threshold.

namespace {
constexpr int kH = 256;
constexpr int kPerRow = 17;                 // (L+1)^2 + 1 with L=3
constexpr int kWaveFloats = 64 * kPerRow;   // 1088 floats = 272 float4
constexpr int kWaveVec4 = kWaveFloats / 4;  // 272
constexpr int kBlocks = 2048;               // 8 blocks/CU on 256 CUs

typedef float f32x4 __attribute__((ext_vector_type(4)));

__global__ __launch_bounds__(kH) void sh_l3_kernel(
    const float* __restrict__ x,
    const float* __restrict__ w_theta, const float* __restrict__ b_theta,
    const float* __restrict__ w_phi,   const float* __restrict__ b_phi,
    const float* __restrict__ w_time,  const float* __restrict__ b_time,
    float* __restrict__ out, int BN, int iters)
{
    __shared__ __align__(16) float lds[kH * kPerRow];  // 17408 B

    const int h    = threadIdx.x;
    const int wave = h >> 6;
    const int lane = h & 63;

    // Weights: loaded ONCE per thread, reused across all iterations.
    const float wt = w_theta[h], bt = b_theta[h];
    const float wp = w_phi[h],   bp = b_phi[h];
    const float wm = w_time[h],  bm = b_time[h];

    float* row = &lds[wave * kWaveFloats + lane * kPerRow];
    const f32x4* lds4 = (const f32x4*)(lds + wave * kWaveFloats);

    // Constant across iterations; LDS chunk is private to this wave.
    row[0] = 0.28209479177387814f;

    const int bn0 = blockIdx.x * iters;
#pragma unroll 1
    for (int it = 0; it < iters; ++it) {
        const int bn = bn0 + it;
        if (bn >= BN) break;

        // Block-uniform scalar inputs.
        const float xt = x[bn * 3 + 0];
        const float xp = x[bn * 3 + 1];
        const float xm = x[bn * 3 + 2];

        const float theta = fmaf(xt, wt, bt);
        const float phi   = fmaf(xp, wp, bp);
        const float tmv   = fmaf(xm, wm, bm);

        // Native HW trig: v_mul(1/2pi) + v_fract + v_sin_f32 / v_cos_f32.
        const float ct  = __cosf(theta);
        const float ct2 = ct * ct;
        const float s   = sqrtf(fmaxf(1.0f - ct2, 0.0f));  // sin(theta) >= 0
        const float ss  = s * s;
        const float sss = ss * s;

        const float sp = __sinf(phi);
        const float cp = __cosf(phi);
        const float c2  = fmaf(2.0f * cp, cp, -1.0f);  // cos 2phi
        const float sn2 = 2.0f * sp * cp;              // sin 2phi
        const float c3  = c2 * cp - sn2 * sp;          // cos 3phi
        const float sn3 = sn2 * cp + c2 * sp;          // sin 3phi

        // K(l,m)*sqrt2 folded with Legendre constants; Condon-Shortley signs:
        //   P11 = -s, P21 = -3 s ct, P31 = -1.5 s (5ct^2-1), P33 = -15 s^3
        row[1]  = -0.4886025119029199f * s * sp;                              // (1,-1)
        row[2]  = 0.4886025119029199f * ct;                                   // (1, 0)
        row[3]  = -0.4886025119029199f * s * cp;                              // (1, 1)
        row[4]  = 0.5462742152960396f * ss * sn2;                             // (2,-2)
        row[5]  = -1.0925484305920792f * (s * ct) * sp;                       // (2,-1)
        row[6]  = 0.31539156525252005f * fmaf(3.0f, ct2, -1.0f);              // (2, 0)
        row[7]  = -1.0925484305920792f * (s * ct) * cp;                       // (2, 1)
        row[8]  = 0.5462742152960396f * ss * c2;                              // (2, 2)
        row[9]  = -0.5900435899266435f * sss * sn3;                           // (3,-3)
        row[10] = 1.445305721320277f * (ss * ct) * sn2;                       // (3,-2)
        row[11] = -0.45704579946446577f * (s * fmaf(5.0f, ct2, -1.0f)) * sp;  // (3,-1)
        row[12] = 0.3731763325901154f * ct * fmaf(5.0f, ct2, -3.0f);          // (3, 0)
        row[13] = -0.45704579946446577f * (s * fmaf(5.0f, ct2, -1.0f)) * cp;  // (3, 1)
        row[14] = 1.445305721320277f * (ss * ct) * c2;                        // (3, 2)
        row[15] = -0.5900435899266435f * sss * c3;                            // (3, 3)
        row[16] = tmv;

        // This wave's DS writes drain; clobber pins the cross-lane LDS reads
        // below after the writes above.
        asm volatile("s_waitcnt lgkmcnt(0)" ::: "memory");

        // Coalesced copy of this wave's 4352 B chunk: 272 float4 / 64 lanes.
        // Plain stores (nt stores regressed 25%, R2).
        f32x4* out4 = (f32x4*)(out + (size_t)bn * (kH * kPerRow) + wave * kWaveFloats);
#pragma unroll
        for (int i = 0; i < 4; ++i)
            out4[i * 64 + lane] = lds4[i * 64 + lane];
        if (lane < kWaveVec4 - 256)  // 16 tail float4s
            out4[256 + lane] = lds4[256 + lane];
    }
}
}  // namespace

extern "C" void kernel_launch(void* const* d_in, const int* in_sizes, int n_in,
                              void* d_out, int out_size, void* d_ws, size_t ws_size,
                              hipStream_t stream) {
    const float* x       = (const float*)d_in[0];
    const float* w_theta = (const float*)d_in[1];
    const float* b_theta = (const float*)d_in[2];
    const float* w_phi   = (const float*)d_in[3];
    const float* b_phi   = (const float*)d_in[4];
    const float* w_time  = (const float*)d_in[5];
    const float* b_time  = (const float*)d_in[6];
    float* out = (float*)d_out;

    const int BN = in_sizes[0] / 3;            // B*N = 16384
    const int nb = BN < kBlocks ? BN : kBlocks;
    const int iters = (BN + nb - 1) / nb;      // 8 for BN=16384
    sh_l3_kernel<<<dim3(nb), dim3(kH), 0, stream>>>(
        x, w_theta, b_theta, w_phi, b_phi, w_time, b_time, out, BN, iters);
}